// Round 11
// baseline (457.600 us; speedup 1.0000x reference)
//
#include <hip/hip_runtime.h>
#include <hip/hip_bf16.h>

typedef __attribute__((ext_vector_type(8))) short s16x8;
typedef __attribute__((ext_vector_type(4))) float f32x4;
typedef __attribute__((ext_vector_type(2))) float f32x2;

__device__ inline unsigned int f2bf(float f) {
    union { float f; unsigned int i; } v;
    v.f = f;
    return (v.i + 0x7FFFu + ((v.i >> 16) & 1u)) >> 16;   // RNE
}
__device__ inline unsigned char f2fp8(float v) {
    const int p = __builtin_amdgcn_cvt_pk_fp8_f32(v, v, 0, false);
    return (unsigned char)(p & 0xFF);
}

// ---------- prep: weight transposes (bf16) + bias concat + zero bin counts ----------
__global__ __launch_bounds__(256) void prep_w(
    const float* __restrict__ Wq, const float* __restrict__ Wk,
    const float* __restrict__ W1, const float* __restrict__ W2,
    const float* __restrict__ Wp,
    const float* __restrict__ bq, const float* __restrict__ bk,
    const float* __restrict__ b1,
    unsigned short* __restrict__ Wtqkt, unsigned short* __restrict__ Wt2,
    unsigned short* __restrict__ Wtp, float* __restrict__ bqkt,
    int* __restrict__ counts, int N)
{
    const int tid = threadIdx.x;
    int b = blockIdx.x;
    if (b < 1024) {                          // 4 x 256x256 weights
        const int w = b >> 8;
        const int i = (b & 255) * 256 + tid;
        const int k = i >> 8, j = i & 255;   // coalesced read of W[k][j]
        const float* W = (w == 0) ? Wq : (w == 1) ? Wk : (w == 2) ? W1 : W2;
        unsigned short* dst = (w == 3) ? Wt2 : (Wtqkt + w * 65536);
        dst[j * 256 + k] = (unsigned short)f2bf(W[i]);
        return;
    }
    b -= 1024;
    if (b < 512) {                           // Wpred [256][512] -> Wtp [512][256]
        const int i = b * 256 + tid;
        const int k = i >> 9, j = i & 511;
        Wtp[(size_t)j * 256 + k] = (unsigned short)f2bf(Wp[i]);
        return;
    }
    b -= 512;
    if (b < 3) {                             // bqkt = [bq | bk | b1]
        const int i = b * 256 + tid;
        bqkt[i] = (i < 256) ? bq[i] : (i < 512) ? bk[i - 256] : b1[i - 512];
        return;
    }
    b -= 3;
    {                                        // zero the sort histogram
        const int i = b * 256 + tid;
        if (i < N) counts[i] = 0;
    }
}

// ---------- sort kernels: bin edges by center node c ----------
__global__ __launch_bounds__(256) void sort_hist(
    const int* __restrict__ node_ids, const int* __restrict__ masked_idx,
    int* __restrict__ counts, int P)
{
    const int e = blockIdx.x * 256 + threadIdx.x;
    if (e >= P) return;
    const int c = node_ids[masked_idx[e]];
    atomicAdd(&counts[c], 1);
}

// single block, 256 threads; exclusive scan over N bins -> cursor
__global__ __launch_bounds__(256) void sort_scan(
    const int* __restrict__ counts, int* __restrict__ cursor, int N)
{
    __shared__ int part[256];
    const int tid = threadIdx.x;
    const int chunk = (N + 255) / 256;
    const int lo = tid * chunk, hi = min(lo + chunk, N);

    int ls = 0;
    for (int i = lo; i < hi; ++i) ls += counts[i];
    part[tid] = ls;
    __syncthreads();
    for (int off = 1; off < 256; off <<= 1) {
        int v = (tid >= off) ? part[tid - off] : 0;
        __syncthreads();
        part[tid] += v;
        __syncthreads();
    }
    int run = part[tid] - ls;                 // exclusive prefix of this chunk
    for (int i = lo; i < hi; ++i) {
        cursor[i] = run;
        run += counts[i];
    }
}

// scatter: sorted[pos] = {e, mi, c, s}
__global__ __launch_bounds__(256) void sort_scatter(
    const int* __restrict__ edge_src, const int* __restrict__ node_ids,
    const int* __restrict__ masked_idx, const int* __restrict__ edge_idx,
    int* __restrict__ cursor, int4* __restrict__ sorted, int P)
{
    const int e = blockIdx.x * 256 + threadIdx.x;
    if (e >= P) return;
    const int mi = masked_idx[e];
    const int c  = node_ids[mi];
    const int s  = edge_src[edge_idx[e]];
    const int pos = atomicAdd(&cursor[c], 1);
    sorted[pos] = make_int4(e, mi, c, s);
}

// ---------- generic MFMA GEMM job ----------
struct GemmJob {
    const void* A;                 // [M][256], f32 (a_f32=1) or bf16
    const unsigned short* Wt;      // [Nout][256] bf16
    const float* bias;             // [Nout] or nullptr
    void* out1;                    // cols [0, split)
    void* out2;                    // cols [split, Nout)
    int Nout;
    int split;
    int relu_lo, relu_hi;          // relu for cols in [relu_lo, relu_hi)
    int a_f32;
    int fp8_1, fp8_2;              // out1/out2 stored as fp8 e4m3 (else bf16)
};

__device__ inline void job_store(const GemmJob& J, int row, int col, float v, int M) {
    if (row >= M) return;
    if (J.bias) v += J.bias[col];
    if (col >= J.relu_lo && col < J.relu_hi) v = fmaxf(v, 0.0f);
    const bool lo = (col < J.split);
    void* o = lo ? J.out1 : J.out2;
    const int stride = lo ? J.split : (J.Nout - J.split);
    const int cc = lo ? col : col - J.split;
    const int f8 = lo ? J.fp8_1 : J.fp8_2;
    if (f8) ((unsigned char*)o)[(size_t)row * stride + cc] = f2fp8(v);
    else    ((unsigned short*)o)[(size_t)row * stride + cc] = (unsigned short)f2bf(v);
}

// Block: 64 rows, 4 waves (2x2), per-wave 32x32 C via 2x2 16x16x32 bf16 frags.
__global__ __launch_bounds__(256) void gemm_multi(
    GemmJob j0, GemmJob j1, int M)
{
    __shared__ __align__(16) char smem[65536];
    char* ldsA = smem;
    char* ldsB = smem + 32768;
    const GemmJob J = (blockIdx.y == 0) ? j0 : j1;

    const int tid  = threadIdx.x;
    const int wid  = tid >> 6, lane = tid & 63;
    const int wr   = wid >> 1, wc = wid & 1;
    const int r0   = blockIdx.x * 64;
    const int swz  = (lane & 7) << 4;

    if (J.a_f32) {
        const float* Af = (const float*)J.A;
        for (int i = tid; i < 2048; i += 256) {
            const int row = i >> 5, off = i & 31;
            const int gr = r0 + row;
            uint4 v = make_uint4(0, 0, 0, 0);
            if (gr < M) {
                const float4 a = *(const float4*)(Af + (size_t)gr * 256 + off * 8);
                const float4 c = *(const float4*)(Af + (size_t)gr * 256 + off * 8 + 4);
                v.x = f2bf(a.x) | (f2bf(a.y) << 16);
                v.y = f2bf(a.z) | (f2bf(a.w) << 16);
                v.z = f2bf(c.x) | (f2bf(c.y) << 16);
                v.w = f2bf(c.z) | (f2bf(c.w) << 16);
            }
            const int b = (row * 512 + off * 16) ^ ((row & 7) << 4);
            *(uint4*)(ldsA + b) = v;
        }
    } else {
        const unsigned short* Ab = (const unsigned short*)J.A;
        for (int i = tid; i < 2048; i += 256) {
            const int row = i >> 5, off = i & 31;
            const int gr = r0 + row;
            uint4 v = make_uint4(0, 0, 0, 0);
            if (gr < M) v = *(const uint4*)(Ab + (size_t)gr * 256 + off * 8);
            const int b = (row * 512 + off * 16) ^ ((row & 7) << 4);
            *(uint4*)(ldsA + b) = v;
        }
    }

    const int ro = lane & 15, ko = (lane >> 4) * 16;
    const int baseA0 = (wr * 32 +  0 + ro) * 512 + ko;
    const int baseA1 = (wr * 32 + 16 + ro) * 512 + ko;
    const int baseB0 = (wc * 32 +  0 + ro) * 512 + ko;
    const int baseB1 = (wc * 32 + 16 + ro) * 512 + ko;

    const int nchunks = J.Nout >> 6;
    for (int c = 0; c < nchunks; ++c) {
        const int j0c = c << 6;
        for (int i = tid; i < 2048; i += 256) {
            const int row = i >> 5, off = i & 31;
            const uint4 v = *(const uint4*)(J.Wt + (size_t)(j0c + row) * 256 + off * 8);
            const int b = (row * 512 + off * 16) ^ ((row & 7) << 4);
            *(uint4*)(ldsB + b) = v;
        }
        __syncthreads();

        f32x4 acc00 = {0,0,0,0}, acc01 = {0,0,0,0}, acc10 = {0,0,0,0}, acc11 = {0,0,0,0};
#pragma unroll
        for (int kk = 0; kk < 8; ++kk) {
            const int kb = kk * 64;
            const s16x8 a0 = *(const s16x8*)(ldsA + ((baseA0 + kb) ^ swz));
            const s16x8 a1 = *(const s16x8*)(ldsA + ((baseA1 + kb) ^ swz));
            const s16x8 b0 = *(const s16x8*)(ldsB + ((baseB0 + kb) ^ swz));
            const s16x8 b1 = *(const s16x8*)(ldsB + ((baseB1 + kb) ^ swz));
            acc00 = __builtin_amdgcn_mfma_f32_16x16x32_bf16(a0, b0, acc00, 0, 0, 0);
            acc01 = __builtin_amdgcn_mfma_f32_16x16x32_bf16(a0, b1, acc01, 0, 0, 0);
            acc10 = __builtin_amdgcn_mfma_f32_16x16x32_bf16(a1, b0, acc10, 0, 0, 0);
            acc11 = __builtin_amdgcn_mfma_f32_16x16x32_bf16(a1, b1, acc11, 0, 0, 0);
        }

        const int colb = j0c + wc * 32;
        const int rb0 = r0 + wr * 32 + (lane >> 4) * 4;
        const int rb1 = rb0 + 16;
#pragma unroll
        for (int r = 0; r < 4; ++r) {
            job_store(J, rb0 + r, colb + ro,      acc00[r], M);
            job_store(J, rb0 + r, colb + 16 + ro, acc01[r], M);
            job_store(J, rb1 + r, colb + ro,      acc10[r], M);
            job_store(J, rb1 + r, colb + 16 + ro, acc11[r], M);
        }
        __syncthreads();
    }
}

// ---------- edge kernel v3: sorted-by-c order, one wave/edge, nt stores ----------
__global__ __launch_bounds__(256) void edge_sorted(
    const int4* __restrict__ sorted,
    const unsigned char* __restrict__ qkb,
    const unsigned char* __restrict__ hp, const unsigned char* __restrict__ gp,
    const float* __restrict__ bpred,
    float* __restrict__ out, int P)
{
    const int wave = threadIdx.x >> 6;
    const int lane = threadIdx.x & 63;
    const int ep = blockIdx.x * 4 + wave;
    if (ep >= P) return;

    const int4 t = sorted[ep];          // wave-uniform 16B load: {e, mi, c, s}
    const int e = t.x, mi = t.y, c = t.z, s = t.w;

    const unsigned int qw = *(const unsigned int*)(qkb + (size_t)c * 512 + lane * 4);
    const unsigned int kw = *(const unsigned int*)(qkb + (size_t)s * 512 + 256 + lane * 4);
    const f32x2 q01 = __builtin_amdgcn_cvt_pk_f32_fp8(qw, false);
    const f32x2 q23 = __builtin_amdgcn_cvt_pk_f32_fp8(qw, true);
    const f32x2 k01 = __builtin_amdgcn_cvt_pk_f32_fp8(kw, false);
    const f32x2 k23 = __builtin_amdgcn_cvt_pk_f32_fp8(kw, true);
    float dot = q01.x * k01.x + q01.y * k01.y + q23.x * k23.x + q23.y * k23.y;
#pragma unroll
    for (int off = 32; off; off >>= 1) dot += __shfl_xor(dot, off, 64);

    const float a = 1.0f / (1.0f + expf(-dot));
    const float oma = 1.0f - a;

    const uint2 hv = *(const uint2*)(hp + (size_t)c * 512 + lane * 8);
    const uint2 gv = *(const uint2*)(gp + (size_t)s * 512 + lane * 8);
    const float4 bp0 = *(const float4*)&bpred[lane * 8];
    const float4 bp1 = *(const float4*)&bpred[lane * 8 + 4];

    const f32x2 h0 = __builtin_amdgcn_cvt_pk_f32_fp8(hv.x, false);
    const f32x2 h1 = __builtin_amdgcn_cvt_pk_f32_fp8(hv.x, true);
    const f32x2 h2 = __builtin_amdgcn_cvt_pk_f32_fp8(hv.y, false);
    const f32x2 h3 = __builtin_amdgcn_cvt_pk_f32_fp8(hv.y, true);
    const f32x2 g0 = __builtin_amdgcn_cvt_pk_f32_fp8(gv.x, false);
    const f32x2 g1 = __builtin_amdgcn_cvt_pk_f32_fp8(gv.x, true);
    const f32x2 g2 = __builtin_amdgcn_cvt_pk_f32_fp8(gv.y, false);
    const f32x2 g3 = __builtin_amdgcn_cvt_pk_f32_fp8(gv.y, true);

    f32x4 r0, r1;
    r0[0] = fmaf(a, h0.x, fmaf(oma, g0.x, bp0.x));
    r0[1] = fmaf(a, h0.y, fmaf(oma, g0.y, bp0.y));
    r0[2] = fmaf(a, h1.x, fmaf(oma, g1.x, bp0.z));
    r0[3] = fmaf(a, h1.y, fmaf(oma, g1.y, bp0.w));
    r1[0] = fmaf(a, h2.x, fmaf(oma, g2.x, bp1.x));
    r1[1] = fmaf(a, h2.y, fmaf(oma, g2.y, bp1.y));
    r1[2] = fmaf(a, h3.x, fmaf(oma, g3.x, bp1.z));
    r1[3] = fmaf(a, h3.y, fmaf(oma, g3.y, bp1.w));

    float* dst = &out[(size_t)e * 512 + lane * 8];
    __builtin_nontemporal_store(r0, (f32x4*)dst);
    __builtin_nontemporal_store(r1, (f32x4*)(dst + 4));

    if (lane == 0) {
        __builtin_nontemporal_store((float)mi, &out[(size_t)P * 512 + e]);
    }
}

extern "C" void kernel_launch(void* const* d_in, const int* in_sizes, int n_in,
                              void* d_out, int out_size, void* d_ws, size_t ws_size,
                              hipStream_t stream) {
    const float* h_mask = (const float*)d_in[0];
    const float* z      = (const float*)d_in[1];
    const float* Wq     = (const float*)d_in[2];
    const float* bq     = (const float*)d_in[3];
    const float* Wk     = (const float*)d_in[4];
    const float* bk     = (const float*)d_in[5];
    const float* W1     = (const float*)d_in[6];
    const float* b1     = (const float*)d_in[7];
    const float* W2     = (const float*)d_in[8];
    const float* b2     = (const float*)d_in[9];
    const float* Wpred  = (const float*)d_in[10];
    const float* bpred  = (const float*)d_in[11];
    const int* edge_index = (const int*)d_in[12];
    const int* node_ids   = (const int*)d_in[13];
    const int* masked_idx = (const int*)d_in[14];
    const int* edge_idx   = (const int*)d_in[15];

    const int N = in_sizes[13];
    const int P = in_sizes[14];

    // ---- workspace layout ----
    unsigned char*  qkb   = (unsigned char*)d_ws;                  // [N][512] fp8 = q|k
    unsigned char*  gpb   = qkb + (size_t)N * 512;                 // [N][512] fp8
    unsigned char*  hpb   = gpb + (size_t)N * 512;                 // [N][512] fp8
    unsigned short* tb    = (unsigned short*)(hpb + (size_t)N * 512);  // [N][256] bf16
    unsigned short* gb    = tb  + (size_t)N * 256;                 // [N][256] bf16
    unsigned short* Wtqkt = gb  + (size_t)N * 256;                 // [768][256] bf16
    unsigned short* Wt2   = Wtqkt + 196608;                        // [256][256]
    unsigned short* Wtp   = Wt2   + 65536;                         // [512][256]
    float*          bqkt  = (float*)(Wtp + 131072);                // [768]
    int*            counts = (int*)(bqkt + 768);                   // [N]
    int*            cursor = counts + N;                           // [N]
    int4*           sorted = (int4*)(cursor + N);                  // [P], 16B-aligned ok

    const dim3 blk(256);
    const int gb64 = (N + 63) / 64;
    const int eb   = (P + 3) / 4;
    const int pb   = (P + 255) / 256;
    const int nb   = (N + 255) / 256;

    // 1. weights prep + zero histogram
    prep_w<<<dim3(1024 + 512 + 3 + nb), blk, 0, stream>>>(
        Wq, Wk, W1, W2, Wpred, bq, bk, b1, Wtqkt, Wt2, Wtp, bqkt, counts, N);

    // 2. sort edges by center node (histogram -> scan -> scatter of {e,mi,c,s})
    sort_hist<<<dim3(pb), blk, 0, stream>>>(node_ids, masked_idx, counts, P);
    sort_scan<<<dim3(1), blk, 0, stream>>>(counts, cursor, N);
    sort_scatter<<<dim3(pb), blk, 0, stream>>>(edge_index, node_ids, masked_idx, edge_idx,
                                               cursor, sorted, P);

    // 3. jobA0: [q|k (fp8) | t (bf16)] = act(z @ [Wq|Wk|W1] + [bq|bk|b1])
    //    jobA1: hp (fp8) = h_mask @ Wpred
    GemmJob a0 = { z,      Wtqkt, bqkt,    qkb, tb,      768, 512, 512, 768, 1, 1, 0 };
    GemmJob a1 = { h_mask, Wtp,   nullptr, hpb, nullptr, 512, 512, 0,   0,   1, 1, 0 };
    gemm_multi<<<dim3(gb64, 2), blk, 0, stream>>>(a0, a1, N);

    // 4. g (bf16) = t @ W2 + b2
    GemmJob b0 = { tb, Wt2, b2, gb, nullptr, 256, 256, 0, 0, 0, 0, 0 };
    gemm_multi<<<dim3(gb64, 1), blk, 0, stream>>>(b0, b0, N);

    // 5. gp (fp8) = g @ Wpred
    GemmJob c0 = { gb, Wtp, nullptr, gpb, nullptr, 512, 512, 0, 0, 0, 1, 0 };
    gemm_multi<<<dim3(gb64, 1), blk, 0, stream>>>(c0, c0, N);

    // 6. edge phase (sorted order, one wave/edge, nt stores)
    edge_sorted<<<dim3(eb), blk, 0, stream>>>(sorted, qkb, hpb, gpb, bpred,
                                              (float*)d_out, P);
}

// Round 12
// 338.916 us; speedup vs baseline: 1.3502x; 1.3502x over previous
//
#include <hip/hip_runtime.h>
#include <hip/hip_bf16.h>

typedef __attribute__((ext_vector_type(8))) short s16x8;
typedef __attribute__((ext_vector_type(4))) float f32x4;
typedef __attribute__((ext_vector_type(2))) float f32x2;

__device__ inline unsigned int f2bf(float f) {
    union { float f; unsigned int i; } v;
    v.f = f;
    return (v.i + 0x7FFFu + ((v.i >> 16) & 1u)) >> 16;   // RNE
}
__device__ inline unsigned char f2fp8(float v) {
    const int p = __builtin_amdgcn_cvt_pk_fp8_f32(v, v, 0, false);
    return (unsigned char)(p & 0xFF);
}

// ---------- prep: weight transposes (bf16) + bias concat ----------
__global__ __launch_bounds__(256) void prep_w(
    const float* __restrict__ Wq, const float* __restrict__ Wk,
    const float* __restrict__ W1, const float* __restrict__ W2,
    const float* __restrict__ Wp,
    const float* __restrict__ bq, const float* __restrict__ bk,
    const float* __restrict__ b1,
    unsigned short* __restrict__ Wtqkt, unsigned short* __restrict__ Wt2,
    unsigned short* __restrict__ Wtp, float* __restrict__ bqkt)
{
    const int tid = threadIdx.x;
    int b = blockIdx.x;
    if (b < 1024) {                          // 4 x 256x256 weights
        const int w = b >> 8;
        const int i = (b & 255) * 256 + tid;
        const int k = i >> 8, j = i & 255;   // coalesced read of W[k][j]
        const float* W = (w == 0) ? Wq : (w == 1) ? Wk : (w == 2) ? W1 : W2;
        unsigned short* dst = (w == 3) ? Wt2 : (Wtqkt + w * 65536);
        dst[j * 256 + k] = (unsigned short)f2bf(W[i]);
        return;
    }
    b -= 1024;
    if (b < 512) {                           // Wpred [256][512] -> Wtp [512][256]
        const int i = b * 256 + tid;
        const int k = i >> 9, j = i & 511;
        Wtp[(size_t)j * 256 + k] = (unsigned short)f2bf(Wp[i]);
        return;
    }
    b -= 512;
    {                                        // bqkt = [bq | bk | b1]
        const int i = b * 256 + tid;
        bqkt[i] = (i < 256) ? bq[i] : (i < 512) ? bk[i - 256] : b1[i - 512];
    }
}

// ---------- idx precompute: cs[e] = {c, s}; out1[e] = (float)masked_idx[e] (coalesced) ----------
__global__ __launch_bounds__(256) void prep_idx(
    const int* __restrict__ edge_src, const int* __restrict__ node_ids,
    const int* __restrict__ masked_idx, const int* __restrict__ edge_idx,
    int2* __restrict__ cs, float* __restrict__ out1, int P)
{
    const int e = blockIdx.x * 256 + threadIdx.x;
    if (e >= P) return;
    const int mi = masked_idx[e];
    const int c  = node_ids[mi];
    const int s  = edge_src[edge_idx[e]];
    cs[e] = make_int2(c, s);
    out1[e] = (float)mi;                     // output 1, fully coalesced full-line writes
}

// ---------- generic MFMA GEMM job ----------
struct GemmJob {
    const void* A;                 // [M][256], f32 (a_f32=1) or bf16
    const unsigned short* Wt;      // [Nout][256] bf16
    const float* bias;             // [Nout] or nullptr
    void* out1;                    // cols [0, split)
    void* out2;                    // cols [split, Nout)
    int Nout;
    int split;
    int relu_lo, relu_hi;          // relu for cols in [relu_lo, relu_hi)
    int a_f32;
    int fp8_1, fp8_2;              // out1/out2 stored as fp8 e4m3 (else bf16)
};

__device__ inline void job_store(const GemmJob& J, int row, int col, float v, int M) {
    if (row >= M) return;
    if (J.bias) v += J.bias[col];
    if (col >= J.relu_lo && col < J.relu_hi) v = fmaxf(v, 0.0f);
    const bool lo = (col < J.split);
    void* o = lo ? J.out1 : J.out2;
    const int stride = lo ? J.split : (J.Nout - J.split);
    const int cc = lo ? col : col - J.split;
    const int f8 = lo ? J.fp8_1 : J.fp8_2;
    if (f8) ((unsigned char*)o)[(size_t)row * stride + cc] = f2fp8(v);
    else    ((unsigned short*)o)[(size_t)row * stride + cc] = (unsigned short)f2bf(v);
}

// Block: 64 rows, 4 waves (2x2), per-wave 32x32 C via 2x2 16x16x32 bf16 frags.
// A tile + B chunk LDS-resident, XOR-swizzled (G4). blockIdx.y selects the job.
__global__ __launch_bounds__(256) void gemm_multi(
    GemmJob j0, GemmJob j1, int M)
{
    __shared__ __align__(16) char smem[65536];
    char* ldsA = smem;
    char* ldsB = smem + 32768;
    const GemmJob J = (blockIdx.y == 0) ? j0 : j1;

    const int tid  = threadIdx.x;
    const int wid  = tid >> 6, lane = tid & 63;
    const int wr   = wid >> 1, wc = wid & 1;
    const int r0   = blockIdx.x * 64;
    const int swz  = (lane & 7) << 4;

    if (J.a_f32) {
        const float* Af = (const float*)J.A;
        for (int i = tid; i < 2048; i += 256) {
            const int row = i >> 5, off = i & 31;
            const int gr = r0 + row;
            uint4 v = make_uint4(0, 0, 0, 0);
            if (gr < M) {
                const float4 a = *(const float4*)(Af + (size_t)gr * 256 + off * 8);
                const float4 c = *(const float4*)(Af + (size_t)gr * 256 + off * 8 + 4);
                v.x = f2bf(a.x) | (f2bf(a.y) << 16);
                v.y = f2bf(a.z) | (f2bf(a.w) << 16);
                v.z = f2bf(c.x) | (f2bf(c.y) << 16);
                v.w = f2bf(c.z) | (f2bf(c.w) << 16);
            }
            const int b = (row * 512 + off * 16) ^ ((row & 7) << 4);
            *(uint4*)(ldsA + b) = v;
        }
    } else {
        const unsigned short* Ab = (const unsigned short*)J.A;
        for (int i = tid; i < 2048; i += 256) {
            const int row = i >> 5, off = i & 31;
            const int gr = r0 + row;
            uint4 v = make_uint4(0, 0, 0, 0);
            if (gr < M) v = *(const uint4*)(Ab + (size_t)gr * 256 + off * 8);
            const int b = (row * 512 + off * 16) ^ ((row & 7) << 4);
            *(uint4*)(ldsA + b) = v;
        }
    }

    const int ro = lane & 15, ko = (lane >> 4) * 16;
    const int baseA0 = (wr * 32 +  0 + ro) * 512 + ko;
    const int baseA1 = (wr * 32 + 16 + ro) * 512 + ko;
    const int baseB0 = (wc * 32 +  0 + ro) * 512 + ko;
    const int baseB1 = (wc * 32 + 16 + ro) * 512 + ko;

    const int nchunks = J.Nout >> 6;
    for (int c = 0; c < nchunks; ++c) {
        const int j0c = c << 6;
        for (int i = tid; i < 2048; i += 256) {
            const int row = i >> 5, off = i & 31;
            const uint4 v = *(const uint4*)(J.Wt + (size_t)(j0c + row) * 256 + off * 8);
            const int b = (row * 512 + off * 16) ^ ((row & 7) << 4);
            *(uint4*)(ldsB + b) = v;
        }
        __syncthreads();

        f32x4 acc00 = {0,0,0,0}, acc01 = {0,0,0,0}, acc10 = {0,0,0,0}, acc11 = {0,0,0,0};
#pragma unroll
        for (int kk = 0; kk < 8; ++kk) {
            const int kb = kk * 64;
            const s16x8 a0 = *(const s16x8*)(ldsA + ((baseA0 + kb) ^ swz));
            const s16x8 a1 = *(const s16x8*)(ldsA + ((baseA1 + kb) ^ swz));
            const s16x8 b0 = *(const s16x8*)(ldsB + ((baseB0 + kb) ^ swz));
            const s16x8 b1 = *(const s16x8*)(ldsB + ((baseB1 + kb) ^ swz));
            acc00 = __builtin_amdgcn_mfma_f32_16x16x32_bf16(a0, b0, acc00, 0, 0, 0);
            acc01 = __builtin_amdgcn_mfma_f32_16x16x32_bf16(a0, b1, acc01, 0, 0, 0);
            acc10 = __builtin_amdgcn_mfma_f32_16x16x32_bf16(a1, b0, acc10, 0, 0, 0);
            acc11 = __builtin_amdgcn_mfma_f32_16x16x32_bf16(a1, b1, acc11, 0, 0, 0);
        }

        const int colb = j0c + wc * 32;
        const int rb0 = r0 + wr * 32 + (lane >> 4) * 4;
        const int rb1 = rb0 + 16;
#pragma unroll
        for (int r = 0; r < 4; ++r) {
            job_store(J, rb0 + r, colb + ro,      acc00[r], M);
            job_store(J, rb0 + r, colb + 16 + ro, acc01[r], M);
            job_store(J, rb1 + r, colb + ro,      acc10[r], M);
            job_store(J, rb1 + r, colb + 16 + ro, acc11[r], M);
        }
        __syncthreads();
    }
}

// ---------- edge kernel: one wave/edge, precomputed {c,s}, nt stores ----------
__global__ __launch_bounds__(256) void edge_fused(
    const int2* __restrict__ cs,
    const unsigned char* __restrict__ qkb,
    const unsigned char* __restrict__ hp, const unsigned char* __restrict__ gp,
    const float* __restrict__ bpred,
    float* __restrict__ out, int P)
{
    const int wave = threadIdx.x >> 6;
    const int lane = threadIdx.x & 63;
    const int e = blockIdx.x * 4 + wave;
    if (e >= P) return;

    const int2 t = cs[e];               // wave-uniform 8B load (broadcast)
    const int c = t.x, s = t.y;

    // dot(q[c], k[s]) — 4 fp8 elems/lane each
    const unsigned int qw = *(const unsigned int*)(qkb + (size_t)c * 512 + lane * 4);
    const unsigned int kw = *(const unsigned int*)(qkb + (size_t)s * 512 + 256 + lane * 4);
    const f32x2 q01 = __builtin_amdgcn_cvt_pk_f32_fp8(qw, false);
    const f32x2 q23 = __builtin_amdgcn_cvt_pk_f32_fp8(qw, true);
    const f32x2 k01 = __builtin_amdgcn_cvt_pk_f32_fp8(kw, false);
    const f32x2 k23 = __builtin_amdgcn_cvt_pk_f32_fp8(kw, true);
    float dot = q01.x * k01.x + q01.y * k01.y + q23.x * k23.x + q23.y * k23.y;
#pragma unroll
    for (int off = 32; off; off >>= 1) dot += __shfl_xor(dot, off, 64);

    const float a = 1.0f / (1.0f + expf(-dot));
    const float oma = 1.0f - a;

    // 8 outputs/lane
    const uint2 hv = *(const uint2*)(hp + (size_t)c * 512 + lane * 8);
    const uint2 gv = *(const uint2*)(gp + (size_t)s * 512 + lane * 8);
    const float4 bp0 = *(const float4*)&bpred[lane * 8];
    const float4 bp1 = *(const float4*)&bpred[lane * 8 + 4];

    const f32x2 h0 = __builtin_amdgcn_cvt_pk_f32_fp8(hv.x, false);
    const f32x2 h1 = __builtin_amdgcn_cvt_pk_f32_fp8(hv.x, true);
    const f32x2 h2 = __builtin_amdgcn_cvt_pk_f32_fp8(hv.y, false);
    const f32x2 h3 = __builtin_amdgcn_cvt_pk_f32_fp8(hv.y, true);
    const f32x2 g0 = __builtin_amdgcn_cvt_pk_f32_fp8(gv.x, false);
    const f32x2 g1 = __builtin_amdgcn_cvt_pk_f32_fp8(gv.x, true);
    const f32x2 g2 = __builtin_amdgcn_cvt_pk_f32_fp8(gv.y, false);
    const f32x2 g3 = __builtin_amdgcn_cvt_pk_f32_fp8(gv.y, true);

    f32x4 r0, r1;
    r0[0] = fmaf(a, h0.x, fmaf(oma, g0.x, bp0.x));
    r0[1] = fmaf(a, h0.y, fmaf(oma, g0.y, bp0.y));
    r0[2] = fmaf(a, h1.x, fmaf(oma, g1.x, bp0.z));
    r0[3] = fmaf(a, h1.y, fmaf(oma, g1.y, bp0.w));
    r1[0] = fmaf(a, h2.x, fmaf(oma, g2.x, bp1.x));
    r1[1] = fmaf(a, h2.y, fmaf(oma, g2.y, bp1.y));
    r1[2] = fmaf(a, h3.x, fmaf(oma, g3.x, bp1.z));
    r1[3] = fmaf(a, h3.y, fmaf(oma, g3.y, bp1.w));

    float* dst = &out[(size_t)e * 512 + lane * 8];
    __builtin_nontemporal_store(r0, (f32x4*)dst);
    __builtin_nontemporal_store(r1, (f32x4*)(dst + 4));
}

extern "C" void kernel_launch(void* const* d_in, const int* in_sizes, int n_in,
                              void* d_out, int out_size, void* d_ws, size_t ws_size,
                              hipStream_t stream) {
    const float* h_mask = (const float*)d_in[0];
    const float* z      = (const float*)d_in[1];
    const float* Wq     = (const float*)d_in[2];
    const float* bq     = (const float*)d_in[3];
    const float* Wk     = (const float*)d_in[4];
    const float* bk     = (const float*)d_in[5];
    const float* W1     = (const float*)d_in[6];
    const float* b1     = (const float*)d_in[7];
    const float* W2     = (const float*)d_in[8];
    const float* b2     = (const float*)d_in[9];
    const float* Wpred  = (const float*)d_in[10];
    const float* bpred  = (const float*)d_in[11];
    const int* edge_index = (const int*)d_in[12];
    const int* node_ids   = (const int*)d_in[13];
    const int* masked_idx = (const int*)d_in[14];
    const int* edge_idx   = (const int*)d_in[15];

    const int N = in_sizes[13];
    const int P = in_sizes[14];

    // ---- workspace layout ----
    unsigned char*  qkb   = (unsigned char*)d_ws;                  // [N][512] fp8 = q|k
    unsigned char*  gpb   = qkb + (size_t)N * 512;                 // [N][512] fp8
    unsigned char*  hpb   = gpb + (size_t)N * 512;                 // [N][512] fp8
    unsigned short* tb    = (unsigned short*)(hpb + (size_t)N * 512);  // [N][256] bf16
    unsigned short* gb    = tb  + (size_t)N * 256;                 // [N][256] bf16
    unsigned short* Wtqkt = gb  + (size_t)N * 256;                 // [768][256] bf16
    unsigned short* Wt2   = Wtqkt + 196608;                        // [256][256]
    unsigned short* Wtp   = Wt2   + 65536;                         // [512][256]
    float*          bqkt  = (float*)(Wtp + 131072);                // [768]
    int2*           cs    = (int2*)(bqkt + 768);                   // [P]

    const dim3 blk(256);
    const int gb64 = (N + 63) / 64;
    const int eb   = (P + 3) / 4;
    const int pb   = (P + 255) / 256;

    // 1. weights prep
    prep_w<<<dim3(1024 + 512 + 3), blk, 0, stream>>>(
        Wq, Wk, W1, W2, Wpred, bq, bk, b1, Wtqkt, Wt2, Wtp, bqkt);

    // 1b. index precompute + coalesced masked_idx output
    prep_idx<<<dim3(pb), blk, 0, stream>>>(edge_index, node_ids, masked_idx, edge_idx,
                                           cs, (float*)d_out + (size_t)P * 512, P);

    // 2. jobA0: [q|k (fp8) | t (bf16)] = act(z @ [Wq|Wk|W1] + [bq|bk|b1])
    //    jobA1: hp (fp8) = h_mask @ Wpred
    GemmJob a0 = { z,      Wtqkt, bqkt,    qkb, tb,      768, 512, 512, 768, 1, 1, 0 };
    GemmJob a1 = { h_mask, Wtp,   nullptr, hpb, nullptr, 512, 512, 0,   0,   1, 1, 0 };
    gemm_multi<<<dim3(gb64, 2), blk, 0, stream>>>(a0, a1, N);

    // 3. g (bf16) = t @ W2 + b2
    GemmJob b0 = { tb, Wt2, b2, gb, nullptr, 256, 256, 0, 0, 0, 0, 0 };
    gemm_multi<<<dim3(gb64, 1), blk, 0, stream>>>(b0, b0, N);

    // 4. gp (fp8) = g @ Wpred
    GemmJob c0 = { gb, Wtp, nullptr, gpb, nullptr, 512, 512, 0, 0, 0, 1, 0 };
    gemm_multi<<<dim3(gb64, 1), blk, 0, stream>>>(c0, c0, N);

    // 5. edge phase (one wave/edge, precomputed indices, nt stores)
    edge_fused<<<dim3(eb), blk, 0, stream>>>(cs, qkb, hpb, gpb, bpred,
                                             (float*)d_out, P);
}

// Round 13
// 316.031 us; speedup vs baseline: 1.4480x; 1.0724x over previous
//
#include <hip/hip_runtime.h>
#include <hip/hip_bf16.h>

typedef __attribute__((ext_vector_type(8))) short s16x8;
typedef __attribute__((ext_vector_type(4))) float f32x4;
typedef __attribute__((ext_vector_type(2))) float f32x2;

__device__ inline unsigned int f2bf(float f) {
    union { float f; unsigned int i; } v;
    v.f = f;
    return (v.i + 0x7FFFu + ((v.i >> 16) & 1u)) >> 16;   // RNE
}
__device__ inline unsigned char f2fp8(float v) {
    const int p = __builtin_amdgcn_cvt_pk_fp8_f32(v, v, 0, false);
    return (unsigned char)(p & 0xFF);
}

// ---------- prep: weight transposes (bf16) + bias concat ----------
__global__ __launch_bounds__(256) void prep_w(
    const float* __restrict__ Wq, const float* __restrict__ Wk,
    const float* __restrict__ W1, const float* __restrict__ W2,
    const float* __restrict__ Wp,
    const float* __restrict__ bq, const float* __restrict__ bk,
    const float* __restrict__ b1,
    unsigned short* __restrict__ Wtqkt, unsigned short* __restrict__ Wt2,
    unsigned short* __restrict__ Wtp, float* __restrict__ bqkt)
{
    const int tid = threadIdx.x;
    int b = blockIdx.x;
    if (b < 1024) {                          // 4 x 256x256 weights
        const int w = b >> 8;
        const int i = (b & 255) * 256 + tid;
        const int k = i >> 8, j = i & 255;   // coalesced read of W[k][j]
        const float* W = (w == 0) ? Wq : (w == 1) ? Wk : (w == 2) ? W1 : W2;
        unsigned short* dst = (w == 3) ? Wt2 : (Wtqkt + w * 65536);
        dst[j * 256 + k] = (unsigned short)f2bf(W[i]);
        return;
    }
    b -= 1024;
    if (b < 512) {                           // Wpred [256][512] -> Wtp [512][256]
        const int i = b * 256 + tid;
        const int k = i >> 9, j = i & 511;
        Wtp[(size_t)j * 256 + k] = (unsigned short)f2bf(Wp[i]);
        return;
    }
    b -= 512;
    {                                        // bqkt = [bq | bk | b1]
        const int i = b * 256 + tid;
        bqkt[i] = (i < 256) ? bq[i] : (i < 512) ? bk[i - 256] : b1[i - 512];
    }
}

// ---------- fused node pipeline, one dispatch ----------
// y=0: per 64-row block: qk = z@[Wq|Wk]+b (fp8 out); t = relu(z@W1+b1) [LDS];
//      g = t@W2+b2 [LDS]; gp = g@Wpred (fp8 out).
// y=1: hp = h_mask@Wpred (fp8 out).
__global__ __launch_bounds__(256) void gemm_fused(
    const float* __restrict__ z, const float* __restrict__ h,
    const unsigned short* __restrict__ Wtqkt, const unsigned short* __restrict__ Wt2,
    const unsigned short* __restrict__ Wtp,
    const float* __restrict__ bqkt, const float* __restrict__ b2,
    unsigned char* __restrict__ qkb, unsigned char* __restrict__ hpb,
    unsigned char* __restrict__ gpb, int M)
{
    __shared__ __align__(16) char smem[65536];
    char* ldsA = smem;
    char* ldsB = smem + 32768;

    const int tid  = threadIdx.x;
    const int wid  = tid >> 6, lane = tid & 63;
    const int wr   = wid >> 1, wc = wid & 1;
    const int r0   = blockIdx.x * 64;
    const int swz  = (lane & 7) << 4;
    const int ro   = lane & 15, ko = (lane >> 4) * 16;
    const int lr0  = wr * 32 + (lane >> 4) * 4;       // local row base of C frags
    const int baseA0 = (wr * 32 +  0 + ro) * 512 + ko;
    const int baseA1 = (wr * 32 + 16 + ro) * 512 + ko;
    const int baseB0 = (wc * 32 +  0 + ro) * 512 + ko;
    const int baseB1 = (wc * 32 + 16 + ro) * 512 + ko;

    f32x4 a00, a01, a10, a11;

    auto stageAf = [&](const float* Af) {
        for (int i = tid; i < 2048; i += 256) {
            const int row = i >> 5, off = i & 31;
            const int gr = r0 + row;
            uint4 v = make_uint4(0, 0, 0, 0);
            if (gr < M) {
                const float4 a = *(const float4*)(Af + (size_t)gr * 256 + off * 8);
                const float4 c = *(const float4*)(Af + (size_t)gr * 256 + off * 8 + 4);
                v.x = f2bf(a.x) | (f2bf(a.y) << 16);
                v.y = f2bf(a.z) | (f2bf(a.w) << 16);
                v.z = f2bf(c.x) | (f2bf(c.y) << 16);
                v.w = f2bf(c.z) | (f2bf(c.w) << 16);
            }
            *(uint4*)(ldsA + ((row * 512 + off * 16) ^ ((row & 7) << 4))) = v;
        }
    };

    // stage 64 B rows (rowbase..+64) into ldsB, sync, run 16 MFMAs against ldsA
    auto chunk = [&](const unsigned short* Wt, int rowbase) {
        for (int i = tid; i < 2048; i += 256) {
            const int row = i >> 5, off = i & 31;
            const uint4 v = *(const uint4*)(Wt + (size_t)(rowbase + row) * 256 + off * 8);
            *(uint4*)(ldsB + ((row * 512 + off * 16) ^ ((row & 7) << 4))) = v;
        }
        __syncthreads();
        a00 = (f32x4){0,0,0,0}; a01 = (f32x4){0,0,0,0};
        a10 = (f32x4){0,0,0,0}; a11 = (f32x4){0,0,0,0};
#pragma unroll
        for (int kk = 0; kk < 8; ++kk) {
            const int kb = kk * 64;
            const s16x8 x0 = *(const s16x8*)(ldsA + ((baseA0 + kb) ^ swz));
            const s16x8 x1 = *(const s16x8*)(ldsA + ((baseA1 + kb) ^ swz));
            const s16x8 y0 = *(const s16x8*)(ldsB + ((baseB0 + kb) ^ swz));
            const s16x8 y1 = *(const s16x8*)(ldsB + ((baseB1 + kb) ^ swz));
            a00 = __builtin_amdgcn_mfma_f32_16x16x32_bf16(x0, y0, a00, 0, 0, 0);
            a01 = __builtin_amdgcn_mfma_f32_16x16x32_bf16(x0, y1, a01, 0, 0, 0);
            a10 = __builtin_amdgcn_mfma_f32_16x16x32_bf16(x1, y0, a10, 0, 0, 0);
            a11 = __builtin_amdgcn_mfma_f32_16x16x32_bf16(x1, y1, a11, 0, 0, 0);
        }
    };

    auto store_fp8 = [&](unsigned char* outb, int colbase, const float* bias) {
        const int cb = colbase + wc * 32;
        const float bs0 = bias ? bias[cb + ro] : 0.0f;
        const float bs1 = bias ? bias[cb + 16 + ro] : 0.0f;
        const int gr0 = r0 + lr0, gr1 = gr0 + 16;
#pragma unroll
        for (int r = 0; r < 4; ++r) {
            if (gr0 + r < M) {
                outb[(size_t)(gr0 + r) * 512 + cb + ro]      = f2fp8(a00[r] + bs0);
                outb[(size_t)(gr0 + r) * 512 + cb + 16 + ro] = f2fp8(a01[r] + bs1);
            }
            if (gr1 + r < M) {
                outb[(size_t)(gr1 + r) * 512 + cb + ro]      = f2fp8(a10[r] + bs0);
                outb[(size_t)(gr1 + r) * 512 + cb + 16 + ro] = f2fp8(a11[r] + bs1);
            }
        }
        __syncthreads();
    };

    // write a bf16-packed fragment set (treg) into ldsA at cols tcbase..  (A-tile layout)
    auto frag_to_ldsA = [&](const unsigned int* treg) {
#pragma unroll
        for (int tc = 0; tc < 4; ++tc) {
            const int cb = tc * 64 + wc * 32;
#pragma unroll
            for (int r = 0; r < 4; ++r) {
                const unsigned int w0 = treg[tc * 8 + r * 2];
                const unsigned int w1 = treg[tc * 8 + r * 2 + 1];
                const int row0 = lr0 + r, row1 = row0 + 16;
                *(unsigned short*)(ldsA + ((row0 * 512 + (cb + ro) * 2)      ^ ((row0 & 7) << 4))) = (unsigned short)(w0 & 0xFFFFu);
                *(unsigned short*)(ldsA + ((row0 * 512 + (cb + 16 + ro) * 2) ^ ((row0 & 7) << 4))) = (unsigned short)(w0 >> 16);
                *(unsigned short*)(ldsA + ((row1 * 512 + (cb + ro) * 2)      ^ ((row1 & 7) << 4))) = (unsigned short)(w1 & 0xFFFFu);
                *(unsigned short*)(ldsA + ((row1 * 512 + (cb + 16 + ro) * 2) ^ ((row1 & 7) << 4))) = (unsigned short)(w1 >> 16);
            }
        }
    };

    if (blockIdx.y == 1) {
        // h-path: hp = h_mask @ Wpred
        stageAf(h);
        for (int c = 0; c < 8; ++c) { chunk(Wtp, c * 64); store_fp8(hpb, c * 64, nullptr); }
        return;
    }

    // ---- z-path ----
    stageAf(z);
    // qk (cols 0..511 of Wtqkt), fp8 out with bias
    for (int c = 0; c < 8; ++c) { chunk(Wtqkt, c * 64); store_fp8(qkb, c * 64, bqkt); }

    // t = relu(z @ W1 + b1) -> registers (Wtqkt rows 512..767)
    unsigned int treg[32];
#pragma unroll
    for (int tc = 0; tc < 4; ++tc) {
        chunk(Wtqkt, 512 + tc * 64);
        const int cb = tc * 64 + wc * 32;
        const float bs0 = bqkt[512 + cb + ro];
        const float bs1 = bqkt[512 + cb + 16 + ro];
#pragma unroll
        for (int r = 0; r < 4; ++r) {
            treg[tc * 8 + r * 2]     = f2bf(fmaxf(a00[r] + bs0, 0.0f)) | (f2bf(fmaxf(a01[r] + bs1, 0.0f)) << 16);
            treg[tc * 8 + r * 2 + 1] = f2bf(fmaxf(a10[r] + bs0, 0.0f)) | (f2bf(fmaxf(a11[r] + bs1, 0.0f)) << 16);
        }
        __syncthreads();
    }
    // t -> ldsA (z dead; last sync above covers all reads)
    frag_to_ldsA(treg);
    __syncthreads();

    // g = t @ W2 + b2 -> registers
#pragma unroll
    for (int gc = 0; gc < 4; ++gc) {
        chunk(Wt2, gc * 64);
        const int cb = gc * 64 + wc * 32;
        const float bs0 = b2[cb + ro];
        const float bs1 = b2[cb + 16 + ro];
#pragma unroll
        for (int r = 0; r < 4; ++r) {
            treg[gc * 8 + r * 2]     = f2bf(a00[r] + bs0) | (f2bf(a01[r] + bs1) << 16);
            treg[gc * 8 + r * 2 + 1] = f2bf(a10[r] + bs0) | (f2bf(a11[r] + bs1) << 16);
        }
        __syncthreads();
    }
    // g -> ldsA
    frag_to_ldsA(treg);
    __syncthreads();

    // gp = g @ Wpred, fp8 out
    for (int c = 0; c < 8; ++c) { chunk(Wtp, c * 64); store_fp8(gpb, c * 64, nullptr); }
}

// ---------- edge kernel (R10 structure: one wave/edge, in-kernel idx, nt stores) ----------
__global__ __launch_bounds__(256) void edge_fused(
    const unsigned char* __restrict__ qkb,
    const unsigned char* __restrict__ hp, const unsigned char* __restrict__ gp,
    const float* __restrict__ bpred,
    const int* __restrict__ edge_src, const int* __restrict__ node_ids,
    const int* __restrict__ masked_idx, const int* __restrict__ edge_idx,
    float* __restrict__ out, int P)
{
    const int wave = threadIdx.x >> 6;
    const int lane = threadIdx.x & 63;
    const int e = blockIdx.x * 4 + wave;
    if (e >= P) return;

    const int mi = masked_idx[e];
    const int c  = node_ids[mi];
    const int s  = edge_src[edge_idx[e]];

    const unsigned int qw = *(const unsigned int*)(qkb + (size_t)c * 512 + lane * 4);
    const unsigned int kw = *(const unsigned int*)(qkb + (size_t)s * 512 + 256 + lane * 4);
    const f32x2 q01 = __builtin_amdgcn_cvt_pk_f32_fp8(qw, false);
    const f32x2 q23 = __builtin_amdgcn_cvt_pk_f32_fp8(qw, true);
    const f32x2 k01 = __builtin_amdgcn_cvt_pk_f32_fp8(kw, false);
    const f32x2 k23 = __builtin_amdgcn_cvt_pk_f32_fp8(kw, true);
    float dot = q01.x * k01.x + q01.y * k01.y + q23.x * k23.x + q23.y * k23.y;
#pragma unroll
    for (int off = 32; off; off >>= 1) dot += __shfl_xor(dot, off, 64);

    const float a = 1.0f / (1.0f + expf(-dot));
    const float oma = 1.0f - a;

    const uint2 hv = *(const uint2*)(hp + (size_t)c * 512 + lane * 8);
    const uint2 gv = *(const uint2*)(gp + (size_t)s * 512 + lane * 8);
    const float4 bp0 = *(const float4*)&bpred[lane * 8];
    const float4 bp1 = *(const float4*)&bpred[lane * 8 + 4];

    const f32x2 h0 = __builtin_amdgcn_cvt_pk_f32_fp8(hv.x, false);
    const f32x2 h1 = __builtin_amdgcn_cvt_pk_f32_fp8(hv.x, true);
    const f32x2 h2 = __builtin_amdgcn_cvt_pk_f32_fp8(hv.y, false);
    const f32x2 h3 = __builtin_amdgcn_cvt_pk_f32_fp8(hv.y, true);
    const f32x2 g0 = __builtin_amdgcn_cvt_pk_f32_fp8(gv.x, false);
    const f32x2 g1 = __builtin_amdgcn_cvt_pk_f32_fp8(gv.x, true);
    const f32x2 g2 = __builtin_amdgcn_cvt_pk_f32_fp8(gv.y, false);
    const f32x2 g3 = __builtin_amdgcn_cvt_pk_f32_fp8(gv.y, true);

    f32x4 r0, r1;
    r0[0] = fmaf(a, h0.x, fmaf(oma, g0.x, bp0.x));
    r0[1] = fmaf(a, h0.y, fmaf(oma, g0.y, bp0.y));
    r0[2] = fmaf(a, h1.x, fmaf(oma, g1.x, bp0.z));
    r0[3] = fmaf(a, h1.y, fmaf(oma, g1.y, bp0.w));
    r1[0] = fmaf(a, h2.x, fmaf(oma, g2.x, bp1.x));
    r1[1] = fmaf(a, h2.y, fmaf(oma, g2.y, bp1.y));
    r1[2] = fmaf(a, h3.x, fmaf(oma, g3.x, bp1.z));
    r1[3] = fmaf(a, h3.y, fmaf(oma, g3.y, bp1.w));

    float* dst = &out[(size_t)e * 512 + lane * 8];
    __builtin_nontemporal_store(r0, (f32x4*)dst);
    __builtin_nontemporal_store(r1, (f32x4*)(dst + 4));

    if (lane == 0) {
        __builtin_nontemporal_store((float)mi, &out[(size_t)P * 512 + e]);
    }
}

extern "C" void kernel_launch(void* const* d_in, const int* in_sizes, int n_in,
                              void* d_out, int out_size, void* d_ws, size_t ws_size,
                              hipStream_t stream) {
    const float* h_mask = (const float*)d_in[0];
    const float* z      = (const float*)d_in[1];
    const float* Wq     = (const float*)d_in[2];
    const float* bq     = (const float*)d_in[3];
    const float* Wk     = (const float*)d_in[4];
    const float* bk     = (const float*)d_in[5];
    const float* W1     = (const float*)d_in[6];
    const float* b1     = (const float*)d_in[7];
    const float* W2     = (const float*)d_in[8];
    const float* b2     = (const float*)d_in[9];
    const float* Wpred  = (const float*)d_in[10];
    const float* bpred  = (const float*)d_in[11];
    const int* edge_index = (const int*)d_in[12];
    const int* node_ids   = (const int*)d_in[13];
    const int* masked_idx = (const int*)d_in[14];
    const int* edge_idx   = (const int*)d_in[15];

    const int N = in_sizes[13];
    const int P = in_sizes[14];

    // ---- workspace layout ----
    unsigned char*  qkb   = (unsigned char*)d_ws;                  // [N][512] fp8 = q|k
    unsigned char*  gpb   = qkb + (size_t)N * 512;                 // [N][512] fp8
    unsigned char*  hpb   = gpb + (size_t)N * 512;                 // [N][512] fp8
    unsigned short* Wtqkt = (unsigned short*)(hpb + (size_t)N * 512);  // [768][256] bf16
    unsigned short* Wt2   = Wtqkt + 196608;                        // [256][256]
    unsigned short* Wtp   = Wt2   + 65536;                         // [512][256]
    float*          bqkt  = (float*)(Wtp + 131072);                // [768]

    const dim3 blk(256);
    const int gb64 = (N + 63) / 64;
    const int eb   = (P + 3) / 4;

    // 1. weights prep
    prep_w<<<dim3(1024 + 512 + 3), blk, 0, stream>>>(
        Wq, Wk, W1, W2, Wpred, bq, bk, b1, Wtqkt, Wt2, Wtp, bqkt);

    // 2. fused node pipeline (y=0: qk,t,g,gp ; y=1: hp)
    gemm_fused<<<dim3(gb64, 2), blk, 0, stream>>>(
        z, h_mask, Wtqkt, Wt2, Wtp, bqkt, b2, qkb, hpb, gpb, N);

    // 3. edge phase (one wave/edge, nt stores)
    edge_fused<<<dim3(eb), blk, 0, stream>>>(qkb, hpb, gpb, bpred,
                                             edge_index, node_ids, masked_idx, edge_idx,
                                             (float*)d_out, P);
}

// Round 14
// 315.629 us; speedup vs baseline: 1.4498x; 1.0013x over previous
//
#include <hip/hip_runtime.h>
#include <hip/hip_bf16.h>

typedef __attribute__((ext_vector_type(8))) short s16x8;
typedef __attribute__((ext_vector_type(4))) float f32x4;
typedef __attribute__((ext_vector_type(2))) float f32x2;

__device__ inline unsigned int f2bf(float f) {
    union { float f; unsigned int i; } v;
    v.f = f;
    return (v.i + 0x7FFFu + ((v.i >> 16) & 1u)) >> 16;   // RNE
}
__device__ inline unsigned char f2fp8(float v) {
    const int p = __builtin_amdgcn_cvt_pk_fp8_f32(v, v, 0, false);
    return (unsigned char)(p & 0xFF);
}

// ---------- prep: weight transposes (bf16) + bias concat ----------
__global__ __launch_bounds__(256) void prep_w(
    const float* __restrict__ Wq, const float* __restrict__ Wk,
    const float* __restrict__ W1, const float* __restrict__ W2,
    const float* __restrict__ Wp,
    const float* __restrict__ bq, const float* __restrict__ bk,
    const float* __restrict__ b1,
    unsigned short* __restrict__ Wtqkt, unsigned short* __restrict__ Wt2,
    unsigned short* __restrict__ Wtp, float* __restrict__ bqkt)
{
    const int tid = threadIdx.x;
    int b = blockIdx.x;
    if (b < 1024) {                          // 4 x 256x256 weights
        const int w = b >> 8;
        const int i = (b & 255) * 256 + tid;
        const int k = i >> 8, j = i & 255;   // coalesced read of W[k][j]
        const float* W = (w == 0) ? Wq : (w == 1) ? Wk : (w == 2) ? W1 : W2;
        unsigned short* dst = (w == 3) ? Wt2 : (Wtqkt + w * 65536);
        dst[j * 256 + k] = (unsigned short)f2bf(W[i]);
        return;
    }
    b -= 1024;
    if (b < 512) {                           // Wpred [256][512] -> Wtp [512][256]
        const int i = b * 256 + tid;
        const int k = i >> 9, j = i & 511;
        Wtp[(size_t)j * 256 + k] = (unsigned short)f2bf(Wp[i]);
        return;
    }
    b -= 512;
    {                                        // bqkt = [bq | bk | b1]
        const int i = b * 256 + tid;
        bqkt[i] = (i < 256) ? bq[i] : (i < 512) ? bk[i - 256] : b1[i - 512];
    }
}

// ---------- fused node pipeline, one dispatch ----------
// Packed tables: qhp[N][768] = [q fp8 (256) | hp fp8 (512)]
//               kgp[N][768] = [k fp8 (256) | gp fp8 (512)]
// y=0: qk = z@[Wq|Wk]+b -> qhp[:,0:256), kgp[:,0:256); t = relu(z@W1+b1) [regs];
//      g = t@W2+b2 [regs->LDS]; gp = g@Wpred -> kgp[:,256:768)
// y=1: hp = h_mask@Wpred -> qhp[:,256:768)
__global__ __launch_bounds__(256) void gemm_fused(
    const float* __restrict__ z, const float* __restrict__ h,
    const unsigned short* __restrict__ Wtqkt, const unsigned short* __restrict__ Wt2,
    const unsigned short* __restrict__ Wtp,
    const float* __restrict__ bqkt, const float* __restrict__ b2,
    unsigned char* __restrict__ qhp, unsigned char* __restrict__ kgp, int M)
{
    __shared__ __align__(16) char smem[65536];
    char* ldsA = smem;
    char* ldsB = smem + 32768;

    const int tid  = threadIdx.x;
    const int wid  = tid >> 6, lane = tid & 63;
    const int wr   = wid >> 1, wc = wid & 1;
    const int r0   = blockIdx.x * 64;
    const int swz  = (lane & 7) << 4;
    const int ro   = lane & 15, ko = (lane >> 4) * 16;
    const int lr0  = wr * 32 + (lane >> 4) * 4;       // local row base of C frags
    const int baseA0 = (wr * 32 +  0 + ro) * 512 + ko;
    const int baseA1 = (wr * 32 + 16 + ro) * 512 + ko;
    const int baseB0 = (wc * 32 +  0 + ro) * 512 + ko;
    const int baseB1 = (wc * 32 + 16 + ro) * 512 + ko;

    f32x4 a00, a01, a10, a11;

    auto stageAf = [&](const float* Af) {
        for (int i = tid; i < 2048; i += 256) {
            const int row = i >> 5, off = i & 31;
            const int gr = r0 + row;
            uint4 v = make_uint4(0, 0, 0, 0);
            if (gr < M) {
                const float4 a = *(const float4*)(Af + (size_t)gr * 256 + off * 8);
                const float4 c = *(const float4*)(Af + (size_t)gr * 256 + off * 8 + 4);
                v.x = f2bf(a.x) | (f2bf(a.y) << 16);
                v.y = f2bf(a.z) | (f2bf(a.w) << 16);
                v.z = f2bf(c.x) | (f2bf(c.y) << 16);
                v.w = f2bf(c.z) | (f2bf(c.w) << 16);
            }
            *(uint4*)(ldsA + ((row * 512 + off * 16) ^ ((row & 7) << 4))) = v;
        }
    };

    // stage 64 B rows (rowbase..+64) into ldsB, sync, run 16 MFMAs against ldsA
    auto chunk = [&](const unsigned short* Wt, int rowbase) {
        for (int i = tid; i < 2048; i += 256) {
            const int row = i >> 5, off = i & 31;
            const uint4 v = *(const uint4*)(Wt + (size_t)(rowbase + row) * 256 + off * 8);
            *(uint4*)(ldsB + ((row * 512 + off * 16) ^ ((row & 7) << 4))) = v;
        }
        __syncthreads();
        a00 = (f32x4){0,0,0,0}; a01 = (f32x4){0,0,0,0};
        a10 = (f32x4){0,0,0,0}; a11 = (f32x4){0,0,0,0};
#pragma unroll
        for (int kk = 0; kk < 8; ++kk) {
            const int kb = kk * 64;
            const s16x8 x0 = *(const s16x8*)(ldsA + ((baseA0 + kb) ^ swz));
            const s16x8 x1 = *(const s16x8*)(ldsA + ((baseA1 + kb) ^ swz));
            const s16x8 y0 = *(const s16x8*)(ldsB + ((baseB0 + kb) ^ swz));
            const s16x8 y1 = *(const s16x8*)(ldsB + ((baseB1 + kb) ^ swz));
            a00 = __builtin_amdgcn_mfma_f32_16x16x32_bf16(x0, y0, a00, 0, 0, 0);
            a01 = __builtin_amdgcn_mfma_f32_16x16x32_bf16(x0, y1, a01, 0, 0, 0);
            a10 = __builtin_amdgcn_mfma_f32_16x16x32_bf16(x1, y0, a10, 0, 0, 0);
            a11 = __builtin_amdgcn_mfma_f32_16x16x32_bf16(x1, y1, a11, 0, 0, 0);
        }
    };

    // store C frags as fp8 into outb rows (stride 768), cols obase+wc*32+{ro,16+ro}
    // bias pre-offset so bias[wc*32 + ro] is correct (or nullptr)
    auto store_fp8 = [&](unsigned char* outb, int obase, const float* bias) {
        const int cb = wc * 32;
        const float bs0 = bias ? bias[cb + ro] : 0.0f;
        const float bs1 = bias ? bias[cb + 16 + ro] : 0.0f;
        const int gr0 = r0 + lr0, gr1 = gr0 + 16;
        const int col0 = obase + cb + ro, col1 = obase + cb + 16 + ro;
#pragma unroll
        for (int r = 0; r < 4; ++r) {
            if (gr0 + r < M) {
                outb[(size_t)(gr0 + r) * 768 + col0] = f2fp8(a00[r] + bs0);
                outb[(size_t)(gr0 + r) * 768 + col1] = f2fp8(a01[r] + bs1);
            }
            if (gr1 + r < M) {
                outb[(size_t)(gr1 + r) * 768 + col0] = f2fp8(a10[r] + bs0);
                outb[(size_t)(gr1 + r) * 768 + col1] = f2fp8(a11[r] + bs1);
            }
        }
        __syncthreads();
    };

    // write a bf16-packed fragment set (treg) into ldsA (A-tile layout)
    auto frag_to_ldsA = [&](const unsigned int* treg) {
#pragma unroll
        for (int tc = 0; tc < 4; ++tc) {
            const int cb = tc * 64 + wc * 32;
#pragma unroll
            for (int r = 0; r < 4; ++r) {
                const unsigned int w0 = treg[tc * 8 + r * 2];
                const unsigned int w1 = treg[tc * 8 + r * 2 + 1];
                const int row0 = lr0 + r, row1 = row0 + 16;
                *(unsigned short*)(ldsA + ((row0 * 512 + (cb + ro) * 2)      ^ ((row0 & 7) << 4))) = (unsigned short)(w0 & 0xFFFFu);
                *(unsigned short*)(ldsA + ((row0 * 512 + (cb + 16 + ro) * 2) ^ ((row0 & 7) << 4))) = (unsigned short)(w0 >> 16);
                *(unsigned short*)(ldsA + ((row1 * 512 + (cb + ro) * 2)      ^ ((row1 & 7) << 4))) = (unsigned short)(w1 & 0xFFFFu);
                *(unsigned short*)(ldsA + ((row1 * 512 + (cb + 16 + ro) * 2) ^ ((row1 & 7) << 4))) = (unsigned short)(w1 >> 16);
            }
        }
    };

    if (blockIdx.y == 1) {
        // h-path: hp = h_mask @ Wpred -> qhp cols 256..767
        stageAf(h);
        for (int c = 0; c < 8; ++c) { chunk(Wtp, c * 64); store_fp8(qhp, 256 + c * 64, nullptr); }
        return;
    }

    // ---- z-path ----
    stageAf(z);
    // q (Wtqkt rows 0..255) -> qhp cols 0..255 ; k (rows 256..511) -> kgp cols 0..255
    for (int c = 0; c < 4; ++c) { chunk(Wtqkt, c * 64);        store_fp8(qhp, c * 64, bqkt + c * 64); }
    for (int c = 0; c < 4; ++c) { chunk(Wtqkt, 256 + c * 64);  store_fp8(kgp, c * 64, bqkt + 256 + c * 64); }

    // t = relu(z @ W1 + b1) -> registers (Wtqkt rows 512..767)
    unsigned int treg[32];
#pragma unroll
    for (int tc = 0; tc < 4; ++tc) {
        chunk(Wtqkt, 512 + tc * 64);
        const int cb = tc * 64 + wc * 32;
        const float bs0 = bqkt[512 + cb + ro];
        const float bs1 = bqkt[512 + cb + 16 + ro];
#pragma unroll
        for (int r = 0; r < 4; ++r) {
            treg[tc * 8 + r * 2]     = f2bf(fmaxf(a00[r] + bs0, 0.0f)) | (f2bf(fmaxf(a01[r] + bs1, 0.0f)) << 16);
            treg[tc * 8 + r * 2 + 1] = f2bf(fmaxf(a10[r] + bs0, 0.0f)) | (f2bf(fmaxf(a11[r] + bs1, 0.0f)) << 16);
        }
        __syncthreads();
    }
    frag_to_ldsA(treg);
    __syncthreads();

    // g = t @ W2 + b2 -> registers
#pragma unroll
    for (int gc = 0; gc < 4; ++gc) {
        chunk(Wt2, gc * 64);
        const int cb = gc * 64 + wc * 32;
        const float bs0 = b2[cb + ro];
        const float bs1 = b2[cb + 16 + ro];
#pragma unroll
        for (int r = 0; r < 4; ++r) {
            treg[gc * 8 + r * 2]     = f2bf(a00[r] + bs0) | (f2bf(a01[r] + bs1) << 16);
            treg[gc * 8 + r * 2 + 1] = f2bf(a10[r] + bs0) | (f2bf(a11[r] + bs1) << 16);
        }
        __syncthreads();
    }
    frag_to_ldsA(treg);
    __syncthreads();

    // gp = g @ Wpred -> kgp cols 256..767
    for (int c = 0; c < 8; ++c) { chunk(Wtp, c * 64); store_fp8(kgp, 256 + c * 64, nullptr); }
}

// ---------- edge kernel: one wave/edge, packed tables, nt stores ----------
// qhp row c: [q | hp]; kgp row s: [k | gp] — 2 random 768B regions per edge.
__global__ __launch_bounds__(256) void edge_fused(
    const unsigned char* __restrict__ qhp, const unsigned char* __restrict__ kgp,
    const float* __restrict__ bpred,
    const int* __restrict__ edge_src, const int* __restrict__ node_ids,
    const int* __restrict__ masked_idx, const int* __restrict__ edge_idx,
    float* __restrict__ out, int P)
{
    const int wave = threadIdx.x >> 6;
    const int lane = threadIdx.x & 63;
    const int e = blockIdx.x * 4 + wave;
    if (e >= P) return;

    const int mi = masked_idx[e];
    const int c  = node_ids[mi];
    const int s  = edge_src[edge_idx[e]];

    const unsigned char* rc = qhp + (size_t)c * 768;
    const unsigned char* rs = kgp + (size_t)s * 768;

    // dot(q[c], k[s]) — 4 fp8 elems/lane each
    const unsigned int qw = *(const unsigned int*)(rc + lane * 4);
    const unsigned int kw = *(const unsigned int*)(rs + lane * 4);
    const f32x2 q01 = __builtin_amdgcn_cvt_pk_f32_fp8(qw, false);
    const f32x2 q23 = __builtin_amdgcn_cvt_pk_f32_fp8(qw, true);
    const f32x2 k01 = __builtin_amdgcn_cvt_pk_f32_fp8(kw, false);
    const f32x2 k23 = __builtin_amdgcn_cvt_pk_f32_fp8(kw, true);
    float dot = q01.x * k01.x + q01.y * k01.y + q23.x * k23.x + q23.y * k23.y;
#pragma unroll
    for (int off = 32; off; off >>= 1) dot += __shfl_xor(dot, off, 64);

    const float a = 1.0f / (1.0f + expf(-dot));
    const float oma = 1.0f - a;

    // 8 outputs/lane
    const uint2 hv = *(const uint2*)(rc + 256 + lane * 8);
    const uint2 gv = *(const uint2*)(rs + 256 + lane * 8);
    const float4 bp0 = *(const float4*)&bpred[lane * 8];
    const float4 bp1 = *(const float4*)&bpred[lane * 8 + 4];

    const f32x2 h0 = __builtin_amdgcn_cvt_pk_f32_fp8(hv.x, false);
    const f32x2 h1 = __builtin_amdgcn_cvt_pk_f32_fp8(hv.x, true);
    const f32x2 h2 = __builtin_amdgcn_cvt_pk_f32_fp8(hv.y, false);
    const f32x2 h3 = __builtin_amdgcn_cvt_pk_f32_fp8(hv.y, true);
    const f32x2 g0 = __builtin_amdgcn_cvt_pk_f32_fp8(gv.x, false);
    const f32x2 g1 = __builtin_amdgcn_cvt_pk_f32_fp8(gv.x, true);
    const f32x2 g2 = __builtin_amdgcn_cvt_pk_f32_fp8(gv.y, false);
    const f32x2 g3 = __builtin_amdgcn_cvt_pk_f32_fp8(gv.y, true);

    f32x4 r0, r1;
    r0[0] = fmaf(a, h0.x, fmaf(oma, g0.x, bp0.x));
    r0[1] = fmaf(a, h0.y, fmaf(oma, g0.y, bp0.y));
    r0[2] = fmaf(a, h1.x, fmaf(oma, g1.x, bp0.z));
    r0[3] = fmaf(a, h1.y, fmaf(oma, g1.y, bp0.w));
    r1[0] = fmaf(a, h2.x, fmaf(oma, g2.x, bp1.x));
    r1[1] = fmaf(a, h2.y, fmaf(oma, g2.y, bp1.y));
    r1[2] = fmaf(a, h3.x, fmaf(oma, g3.x, bp1.z));
    r1[3] = fmaf(a, h3.y, fmaf(oma, g3.y, bp1.w));

    float* dst = &out[(size_t)e * 512 + lane * 8];
    __builtin_nontemporal_store(r0, (f32x4*)dst);
    __builtin_nontemporal_store(r1, (f32x4*)(dst + 4));

    if (lane == 0) {
        __builtin_nontemporal_store((float)mi, &out[(size_t)P * 512 + e]);
    }
}

extern "C" void kernel_launch(void* const* d_in, const int* in_sizes, int n_in,
                              void* d_out, int out_size, void* d_ws, size_t ws_size,
                              hipStream_t stream) {
    const float* h_mask = (const float*)d_in[0];
    const float* z      = (const float*)d_in[1];
    const float* Wq     = (const float*)d_in[2];
    const float* bq     = (const float*)d_in[3];
    const float* Wk     = (const float*)d_in[4];
    const float* bk     = (const float*)d_in[5];
    const float* W1     = (const float*)d_in[6];
    const float* b1     = (const float*)d_in[7];
    const float* W2     = (const float*)d_in[8];
    const float* b2     = (const float*)d_in[9];
    const float* Wpred  = (const float*)d_in[10];
    const float* bpred  = (const float*)d_in[11];
    const int* edge_index = (const int*)d_in[12];
    const int* node_ids   = (const int*)d_in[13];
    const int* masked_idx = (const int*)d_in[14];
    const int* edge_idx   = (const int*)d_in[15];

    const int N = in_sizes[13];
    const int P = in_sizes[14];

    // ---- workspace layout ----
    unsigned char*  qhp   = (unsigned char*)d_ws;                  // [N][768] fp8 = q|hp
    unsigned char*  kgp   = qhp + (size_t)N * 768;                 // [N][768] fp8 = k|gp
    unsigned short* Wtqkt = (unsigned short*)(kgp + (size_t)N * 768);  // [768][256] bf16
    unsigned short* Wt2   = Wtqkt + 196608;                        // [256][256]
    unsigned short* Wtp   = Wt2   + 65536;                         // [512][256]
    float*          bqkt  = (float*)(Wtp + 131072);                // [768]

    const dim3 blk(256);
    const int gb64 = (N + 63) / 64;
    const int eb   = (P + 3) / 4;

    // 1. weights prep
    prep_w<<<dim3(1024 + 512 + 3), blk, 0, stream>>>(
        Wq, Wk, W1, W2, Wpred, bq, bk, b1, Wtqkt, Wt2, Wtp, bqkt);

    // 2. fused node pipeline (y=0: q,k,t,g,gp ; y=1: hp), packed-table outputs
    gemm_fused<<<dim3(gb64, 2), blk, 0, stream>>>(
        z, h_mask, Wtqkt, Wt2, Wtp, bqkt, b2, qhp, kgp, N);

    // 3. edge phase (one wave/edge, 2 packed gathers, nt stores)
    edge_fused<<<dim3(eb), blk, 0, stream>>>(qhp, kgp, bpred,
                                             edge_index, node_ids, masked_idx, edge_idx,
                                             (float*)d_out, P);
}